// Round 9
// baseline (180.019 us; speedup 1.0000x reference)
//
#include <hip/hip_runtime.h>
#include <hip/hip_bf16.h>

#define NN 8192
#define DD 256
#define BM 128
#define BN 128
#define BK 32

typedef __bf16 bf16x8 __attribute__((ext_vector_type(8)));
typedef float f32x4 __attribute__((ext_vector_type(4)));

__device__ inline void gload_lds16(const void* g, void* l) {
  __builtin_amdgcn_global_load_lds(
      (const __attribute__((address_space(1))) void*)g,
      (__attribute__((address_space(3))) void*)l, 16, 0, 0);
}

// ---------------- prep: rnorm + bf16 hi/lo split ----------------
__global__ __launch_bounds__(256) void prep_kernel(
    const float* __restrict__ Z,
    __hip_bfloat16* __restrict__ Zhi,
    __hip_bfloat16* __restrict__ Zlo,
    float* __restrict__ rnorm) {
  const int gtid = blockIdx.x * 256 + threadIdx.x;
  const int row  = gtid >> 6;          // one wave per row
  const int lane = threadIdx.x & 63;
  if (row >= NN) return;

  const float4 v = reinterpret_cast<const float4*>(Z + (size_t)row * DD)[lane];
  float ss = v.x * v.x + v.y * v.y + v.z * v.z + v.w * v.w;
#pragma unroll
  for (int off = 32; off > 0; off >>= 1) ss += __shfl_xor(ss, off);
  if (lane == 0) rnorm[row] = 1.0f / fmaxf(sqrtf(ss), 1e-8f);

  float f[4] = {v.x, v.y, v.z, v.w};
  unsigned short hi[4], lo[4];
#pragma unroll
  for (int i = 0; i < 4; ++i) {
    __hip_bfloat16 h = __float2bfloat16(f[i]);
    float hf = __bfloat162float(h);
    __hip_bfloat16 l = __float2bfloat16(f[i] - hf);
    hi[i] = *reinterpret_cast<unsigned short*>(&h);
    lo[i] = *reinterpret_cast<unsigned short*>(&l);
  }
  ushort4 hv = make_ushort4(hi[0], hi[1], hi[2], hi[3]);
  ushort4 lv = make_ushort4(lo[0], lo[1], lo[2], lo[3]);
  reinterpret_cast<ushort4*>(Zhi + (size_t)row * DD)[lane] = hv;
  reinterpret_cast<ushort4*>(Zlo + (size_t)row * DD)[lane] = lv;
}

// LDS: staging (32 KB) + full-tile transpose buffer (66 KB) -- DISJOINT.
struct __attribute__((aligned(16))) SharedT {
  __hip_bfloat16 Ah[BM * BK];
  __hip_bfloat16 Al[BM * BK];
  __hip_bfloat16 Bh[BN * BK];
  __hip_bfloat16 Bl[BN * BK];
  float tb[BM * 129];          // pad 129: row reads AND col reads conflict-free
};

// ---- producer/consumer 2-tile pipelined Gram + dual epilogue ----
// waves 0-3: K-loop MFMA producers; waves 4-7: epilogue store consumers.
__global__ __launch_bounds__(512, 2) void gram_kernel(
    const __hip_bfloat16* __restrict__ Zhi,
    const __hip_bfloat16* __restrict__ Zlo,
    const float* __restrict__ rnorm,
    const int* __restrict__ batch,
    float* __restrict__ outA,
    float* __restrict__ outS) {
  __shared__ SharedT sh;

  const int tid  = threadIdx.x;
  const int lane = tid & 63;
  const int wid  = tid >> 6;
  const bool comp = (wid < 4);
  const int w4   = wid - 4;      // consumer wave id 0..3
  const int wr   = wid >> 1;     // producer 2x2 wave grid
  const int wc   = wid & 1;
  const int lr   = lane >> 4;
  const int lc   = lane & 15;

  // XCD-swizzled tile-pair id (1040 = 8*130, bijective)
  const int b = blockIdx.x;
  const int s = (b & 7) * 130 + (b >> 3);

  f32x4 acc[4][4];
  int   prow0 = 0, pcol0 = 0;
  bool  pmir = false;
  float rnA0 = 0, rnA1 = 0, rnB0 = 0, rnB1 = 0;
  int   btA0 = 0, btA1 = 0, btB0 = 0, btB1 = 0;

  // one consumer epilogue op: dop in [0,256): r=dop>>1, half=dop&1
  auto do_op = [&](int dop, bool mop) {
    const int r = dop >> 1;
    const int h = dop & 1;
    float g, rnAv, rnBv;
    int btAv, btBv;
    size_t o;
    if (!mop) {                       // direct: row prow0+r, cols pcol0+h*64+..
      g = sh.tb[r * 129 + h * 64 + lane];
      const float va = (r < 64) ? rnA0 : rnA1;
      const int   ba = (r < 64) ? btA0 : btA1;
      rnAv = __shfl(va, r & 63);
      btAv = __shfl(ba, r & 63);
      rnBv = h ? rnB1 : rnB0;
      btBv = h ? btB1 : btB0;
      o = (size_t)(prow0 + r) * NN + (pcol0 + h * 64 + lane);
    } else {                          // mirror: row pcol0+r, cols prow0+h*64+..
      g = sh.tb[(h * 64 + lane) * 129 + r];
      const float vb = (r < 64) ? rnB0 : rnB1;
      const int   bb = (r < 64) ? btB0 : btB1;
      rnBv = __shfl(vb, r & 63);
      btBv = __shfl(bb, r & 63);
      rnAv = h ? rnA1 : rnA0;
      btAv = h ? btA1 : btA0;
      o = (size_t)(pcol0 + r) * NN + (prow0 + h * 64 + lane);
    }
    const float a  = __builtin_amdgcn_rcpf(1.0f + __expf(-g));
    const float sv = (btAv == btBv) ? g * rnAv * rnBv : 0.0f;
    outA[o] = a;
    outS[o] = sv;
  };
  auto chunk = [&](int cq) {          // 4 direct (+4 mirror) ops per wave
#pragma unroll
    for (int i = 0; i < 4; ++i) do_op(cq * 16 + w4 * 4 + i, false);
    if (pmir) {
#pragma unroll
      for (int i = 0; i < 4; ++i) do_op(cq * 16 + w4 * 4 + i, true);
    }
  };

  for (int t = 0; t < 2; ++t) {
    const int idx = 2 * s + t;
    // triangular decode: idx -> (brow <= bcol)
    int bcol = (int)((sqrtf(8.0f * (float)idx + 1.0f) - 1.0f) * 0.5f);
    while ((bcol + 1) * (bcol + 2) / 2 <= idx) ++bcol;
    while (bcol * (bcol + 1) / 2 > idx) --bcol;
    const int brow = idx - bcol * (bcol + 1) / 2;
    const int row0 = brow * BM, col0 = bcol * BN;

    if (comp) {
#pragma unroll
      for (int m = 0; m < 4; ++m)
#pragma unroll
        for (int n = 0; n < 4; ++n) acc[m][n] = (f32x4){0, 0, 0, 0};
    }

    for (int kt = 0; kt < DD / BK; ++kt) {
      if (comp) {
        const int k0 = kt * BK;
#pragma unroll
        for (int c = 0; c < 2; ++c) {
          const int ci  = c * 256 + tid;           // tid 0..255 here
          const int r   = ci >> 2;
          const int ch  = ci & 3;
          const int chg = ch ^ ((r >> 1) & 3);     // swizzle involution
          const int base = (c * 256 + wid * 64) * 16;
          const size_t ga = (size_t)(row0 + r) * DD + k0 + chg * 8;
          const size_t gb = (size_t)(col0 + r) * DD + k0 + chg * 8;
          gload_lds16(Zhi + ga, (char*)sh.Ah + base);
          gload_lds16(Zlo + ga, (char*)sh.Al + base);
          gload_lds16(Zhi + gb, (char*)sh.Bh + base);
          gload_lds16(Zlo + gb, (char*)sh.Bl + base);
        }
      } else if (t) chunk(2 * kt);
      __syncthreads();
      if (comp) {
        bf16x8 fa[4], fb[4], ft[4];
#pragma unroll
        for (int m = 0; m < 4; ++m) {
          const int rA = wr * 64 + m * 16 + lc;
          const int off = rA * BK + ((lr ^ ((rA >> 1) & 3)) << 3);
          fa[m] = *reinterpret_cast<const bf16x8*>(&sh.Ah[off]);
        }
#pragma unroll
        for (int n = 0; n < 4; ++n) {
          const int rB = wc * 64 + n * 16 + lc;
          const int off = rB * BK + ((lr ^ ((rB >> 1) & 3)) << 3);
          fb[n] = *reinterpret_cast<const bf16x8*>(&sh.Bh[off]);
        }
#pragma unroll
        for (int m = 0; m < 4; ++m)
#pragma unroll
          for (int n = 0; n < 4; ++n)
            acc[m][n] = __builtin_amdgcn_mfma_f32_16x16x32_bf16(fa[m], fb[n], acc[m][n], 0, 0, 0);
#pragma unroll
        for (int m = 0; m < 4; ++m) {
          const int rA = wr * 64 + m * 16 + lc;
          const int off = rA * BK + ((lr ^ ((rA >> 1) & 3)) << 3);
          ft[m] = *reinterpret_cast<const bf16x8*>(&sh.Al[off]);
        }
#pragma unroll
        for (int m = 0; m < 4; ++m)
#pragma unroll
          for (int n = 0; n < 4; ++n)
            acc[m][n] = __builtin_amdgcn_mfma_f32_16x16x32_bf16(ft[m], fb[n], acc[m][n], 0, 0, 0);
#pragma unroll
        for (int n = 0; n < 4; ++n) {
          const int rB = wc * 64 + n * 16 + lc;
          const int off = rB * BK + ((lr ^ ((rB >> 1) & 3)) << 3);
          fb[n] = *reinterpret_cast<const bf16x8*>(&sh.Bl[off]);
        }
#pragma unroll
        for (int m = 0; m < 4; ++m)
#pragma unroll
          for (int n = 0; n < 4; ++n)
            acc[m][n] = __builtin_amdgcn_mfma_f32_16x16x32_bf16(fa[m], fb[n], acc[m][n], 0, 0, 0);
      } else if (t) chunk(2 * kt + 1);
      __syncthreads();
    }

    __syncthreads();   // consumers done with tb(prev); producers done with K
    if (comp) {
      // dump acc -> tb (4-way bank alias, once per tile: cheap)
#pragma unroll
      for (int m = 0; m < 4; ++m)
#pragma unroll
        for (int n = 0; n < 4; ++n)
#pragma unroll
          for (int j = 0; j < 4; ++j)
            sh.tb[(wr * 64 + m * 16 + lr * 4 + j) * 129 + wc * 64 + n * 16 + lc] =
                acc[m][n][j];
    } else {
      // preload norm/batch regs for THIS tile (consumed next iteration/tail)
      rnA0 = rnorm[row0 + lane];      rnA1 = rnorm[row0 + 64 + lane];
      btA0 = batch[row0 + lane];      btA1 = batch[row0 + 64 + lane];
      rnB0 = rnorm[col0 + lane];      rnB1 = rnorm[col0 + 64 + lane];
      btB0 = batch[col0 + lane];      btB1 = batch[col0 + 64 + lane];
    }
    __syncthreads();   // tb(cur) published; regs ready
    prow0 = row0; pcol0 = col0; pmir = (brow != bcol);
  }

  // tail: consumers drain the last tile barrier-free; producers exit
  if (!comp) {
    for (int cq = 0; cq < 16; ++cq) chunk(cq);
  }
}

extern "C" void kernel_launch(void* const* d_in, const int* in_sizes, int n_in,
                              void* d_out, int out_size, void* d_ws, size_t ws_size,
                              hipStream_t stream) {
  const float* Z     = (const float*)d_in[0];
  const int*   batch = (const int*)d_in[1];
  float* out = (float*)d_out;

  __hip_bfloat16* Zhi = (__hip_bfloat16*)d_ws;
  __hip_bfloat16* Zlo = Zhi + (size_t)NN * DD;
  float* rnorm = (float*)(Zlo + (size_t)NN * DD);

  prep_kernel<<<NN / 4, 256, 0, stream>>>(Z, Zhi, Zlo, rnorm);

  // 2080 tiles, 2 per block -> 1040 blocks of 512 threads
  gram_kernel<<<dim3(1040), 512, 0, stream>>>(Zhi, Zlo, rnorm, batch, out,
                                              out + (size_t)NN * NN);
}